// Round 1
// baseline (1804.968 us; speedup 1.0000x reference)
//
#include <hip/hip_runtime.h>

#define NLAYER 3
#define NATOM 20000
#define NPROBE 100000
#define NEDGE 400000
#define HD 128
#define NBIN 2048
#define CUTOFFF 4.0f

// ---------- math helpers ----------
__device__ __forceinline__ float sspf(float x) {
    // softplus(x) - log(2), stable
    return fmaxf(x, 0.f) + __logf(1.f + __expf(-fabsf(x))) - 0.69314718055994530942f;
}
__device__ __forceinline__ float sigf(float x) {
    return 1.f / (1.f + __expf(-x));
}
__device__ __forceinline__ void atomic_add_f(float* p, float v) {
    __hip_atomic_fetch_add(p, v, __ATOMIC_RELAXED, __HIP_MEMORY_SCOPE_AGENT);
}

// ---------- shared GEMM building blocks ----------
// Block = 256 threads, tile = 64 rows x 128 cols, K = 128.
// Thread (jg = t&63, eg = t>>6) computes cols {jg, jg+64} for rows eg*16..eg*16+15.
// A is staged transposed in LDS: At[k][row], stride 68 keeps float4 alignment.

__device__ __forceinline__ void stage_rows(const float* __restrict__ A, int M,
                                           int m0, int t, float (*At)[68]) {
    int r = t >> 2, q = t & 3;
    int row = m0 + r;
    const float* src = A + (size_t)row * HD + q * 32;
#pragma unroll
    for (int i4 = 0; i4 < 8; ++i4) {
        float4 v = make_float4(0.f, 0.f, 0.f, 0.f);
        if (row < M) v = *(const float4*)(src + i4 * 4);
        int k = q * 32 + i4 * 4;
        At[k + 0][r] = v.x; At[k + 1][r] = v.y;
        At[k + 2][r] = v.z; At[k + 3][r] = v.w;
    }
}

__device__ __forceinline__ void gemm_tile(const float* __restrict__ W,
                                          const float (*At)[68],
                                          int jg, int eg,
                                          float* acc0, float* acc1) {
#pragma unroll 4
    for (int k = 0; k < HD; ++k) {
        float w0 = W[k * HD + jg];
        float w1 = W[k * HD + jg + 64];
        const float* a = &At[k][eg * 16];
#pragma unroll
        for (int r4 = 0; r4 < 4; ++r4) {
            float4 av = *(const float4*)(a + r4 * 4);
            acc0[r4 * 4 + 0] = fmaf(av.x, w0, acc0[r4 * 4 + 0]);
            acc1[r4 * 4 + 0] = fmaf(av.x, w1, acc1[r4 * 4 + 0]);
            acc0[r4 * 4 + 1] = fmaf(av.y, w0, acc0[r4 * 4 + 1]);
            acc1[r4 * 4 + 1] = fmaf(av.y, w1, acc1[r4 * 4 + 1]);
            acc0[r4 * 4 + 2] = fmaf(av.z, w0, acc0[r4 * 4 + 2]);
            acc1[r4 * 4 + 2] = fmaf(av.z, w1, acc1[r4 * 4 + 2]);
            acc0[r4 * 4 + 3] = fmaf(av.w, w0, acc0[r4 * 4 + 3]);
            acc1[r4 * 4 + 3] = fmaf(av.w, w1, acc1[r4 * 4 + 3]);
        }
    }
}

// ---------- gates lookup table ----------
// gtab[l][i][j] = (mlp(edge_state(d_i), We1,be1,We2,be2) * soft_cut(d_i))[j],
// d_i = i * CUTOFF/NBIN, i = 0..NBIN.
__global__ void gate_table_k(const float* __restrict__ We1, const float* __restrict__ be1,
                             const float* __restrict__ We2, const float* __restrict__ be2,
                             float* __restrict__ gtab) {
    int row = blockIdx.x;                 // l*(NBIN+1) + i
    int l = row / (NBIN + 1);
    int i = row % (NBIN + 1);
    int j = threadIdx.x;                  // 0..127
    float d = (CUTOFFF / NBIN) * (float)i;
    __shared__ float h1[HD];
    const float* w1 = We1 + (size_t)l * 16 * HD;
    float acc = be1[l * HD + j];
#pragma unroll
    for (int k = 0; k < 16; ++k) {
        float dd = d - 0.25f * (float)k;
        float es = __expf(-dd * dd * 8.0f);   // exp(-(d-mu)^2 / (2*0.25^2))
        acc = fmaf(es, w1[k * HD + j], acc);
    }
    h1[j] = sspf(acc);
    __syncthreads();
    const float* w2 = We2 + (size_t)l * HD * HD;
    float acc2 = be2[l * HD + j];
    for (int k = 0; k < HD; ++k) acc2 = fmaf(h1[k], w2[k * HD + j], acc2);
    float sc = 1.f - sigf(5.f * (d - (CUTOFFF - 1.5f)));
    gtab[(size_t)row * HD + j] = acc2 * sc;
}

// ---------- generic single-stage GEMM (no bias, no activation) ----------
__global__ __launch_bounds__(256) void gemm1_k(const float* __restrict__ A, int M,
                                               const float* __restrict__ W,
                                               float* __restrict__ outp) {
    __shared__ float At[HD][68];
    int m0 = blockIdx.x * 64;
    int t = threadIdx.x;
    stage_rows(A, M, m0, t, At);
    __syncthreads();
    int jg = t & 63, eg = t >> 6;
    float acc0[16], acc1[16];
#pragma unroll
    for (int i = 0; i < 16; ++i) { acc0[i] = 0.f; acc1[i] = 0.f; }
    gemm_tile(W, At, jg, eg, acc0, acc1);
#pragma unroll 4
    for (int r8 = 0; r8 < 16; ++r8) {
        int row = m0 + eg * 16 + r8;
        if (row < M) {
            outp[(size_t)row * HD + jg] = acc0[r8];
            outp[(size_t)row * HD + jg + 64] = acc1[r8];
        }
    }
}

// ---------- edge kernel: h = ssp(Xa[snd]+Xp[rcv]+bn1); msg = (h@Wn2+bn2)*gate(d); scatter ----------
__global__ __launch_bounds__(256) void edge_msg_k(
        const float* __restrict__ Xa, const float* __restrict__ Xp,
        const float* __restrict__ bn1, const float* __restrict__ Wn2,
        const float* __restrict__ bn2, const float* __restrict__ gtab,
        const float* __restrict__ dist, const int* __restrict__ pe,
        float* __restrict__ msgsum) {
    __shared__ float At[HD][68];
    __shared__ int rcv_s[64];
    __shared__ float d_s[64];
    int e0 = blockIdx.x * 64;
    int t = threadIdx.x;
    if (t < 64) {
        rcv_s[t] = pe[2 * (e0 + t) + 1];
        d_s[t] = dist[e0 + t];
    }
    {
        int r = t >> 2, q = t & 3;
        int e = e0 + r;
        int snd = pe[2 * e];
        int rcv = pe[2 * e + 1];
        const float* xa = Xa + (size_t)snd * HD + q * 32;
        const float* xp = Xp + (size_t)rcv * HD + q * 32;
        const float* bb = bn1 + q * 32;
#pragma unroll
        for (int i4 = 0; i4 < 8; ++i4) {
            float4 va = *(const float4*)(xa + i4 * 4);
            float4 vp = *(const float4*)(xp + i4 * 4);
            float4 vb = *(const float4*)(bb + i4 * 4);
            int k = q * 32 + i4 * 4;
            At[k + 0][r] = sspf(va.x + vp.x + vb.x);
            At[k + 1][r] = sspf(va.y + vp.y + vb.y);
            At[k + 2][r] = sspf(va.z + vp.z + vb.z);
            At[k + 3][r] = sspf(va.w + vp.w + vb.w);
        }
    }
    __syncthreads();
    int jg = t & 63, eg = t >> 6;
    float acc0[16], acc1[16];
#pragma unroll
    for (int i = 0; i < 16; ++i) { acc0[i] = 0.f; acc1[i] = 0.f; }
    gemm_tile(Wn2, At, jg, eg, acc0, acc1);
    float b20 = bn2[jg], b21 = bn2[jg + 64];
#pragma unroll 4
    for (int r8 = 0; r8 < 16; ++r8) {
        int r = eg * 16 + r8;
        float d = d_s[r];
        float x = d * ((float)NBIN / CUTOFFF);
        int i = (int)x;
        i = i < (NBIN - 1) ? i : (NBIN - 1);
        float f = x - (float)i;
        const float* g0 = gtab + (size_t)i * HD;
        float ga0 = g0[jg],      gb0 = g0[HD + jg];
        float ga1 = g0[jg + 64], gb1 = g0[HD + jg + 64];
        float gj0 = fmaf(gb0 - ga0, f, ga0);
        float gj1 = fmaf(gb1 - ga1, f, ga1);
        float* dst = msgsum + (size_t)rcv_s[r] * HD;
        atomic_add_f(dst + jg,      (acc0[r8] + b20) * gj0);
        atomic_add_f(dst + jg + 64, (acc1[r8] + b21) * gj1);
    }
}

// ---------- fused 2-layer MLP over probes ----------
// mode 0: outp[p] = sigmoid(ssp(A@W1+b1)@W2+b2)           (gate vector)
// mode 1: outp[p] = psin[p]*Gp[p] + (1-Gp[p])*(ssp(A@W1+b1)@W2+b2)   (state update)
__global__ __launch_bounds__(256) void mlp2_k(
        const float* __restrict__ A,
        const float* __restrict__ W1, const float* __restrict__ b1,
        const float* __restrict__ W2, const float* __restrict__ b2,
        float* __restrict__ outp, const float* __restrict__ Gp,
        const float* __restrict__ psin, int mode) {
    __shared__ float At[HD][68];
    int m0 = blockIdx.x * 64;
    int t = threadIdx.x;
    stage_rows(A, NPROBE, m0, t, At);
    __syncthreads();
    int jg = t & 63, eg = t >> 6;
    float acc0[16], acc1[16];
#pragma unroll
    for (int i = 0; i < 16; ++i) { acc0[i] = 0.f; acc1[i] = 0.f; }
    gemm_tile(W1, At, jg, eg, acc0, acc1);
    float bb0 = b1[jg], bb1 = b1[jg + 64];
    __syncthreads();                       // everyone done reading At
#pragma unroll
    for (int r8 = 0; r8 < 16; ++r8) {      // write hidden (transposed) back into At
        At[jg][eg * 16 + r8]      = sspf(acc0[r8] + bb0);
        At[jg + 64][eg * 16 + r8] = sspf(acc1[r8] + bb1);
    }
    __syncthreads();
#pragma unroll
    for (int i = 0; i < 16; ++i) { acc0[i] = 0.f; acc1[i] = 0.f; }
    gemm_tile(W2, At, jg, eg, acc0, acc1);
    float c0 = b2[jg], c1 = b2[jg + 64];
#pragma unroll 4
    for (int r8 = 0; r8 < 16; ++r8) {
        int row = m0 + eg * 16 + r8;
        if (row < NPROBE) {
            size_t o = (size_t)row * HD + jg;
            if (mode == 0) {
                outp[o]      = sigf(acc0[r8] + c0);
                outp[o + 64] = sigf(acc1[r8] + c1);
            } else {
                float g0v = Gp[o], g1v = Gp[o + 64];
                float t0 = acc0[r8] + c0, t1 = acc1[r8] + c1;
                outp[o]      = psin[o] * g0v + (1.f - g0v) * t0;
                outp[o + 64] = psin[o + 64] * g1v + (1.f - g1v) * t1;
            }
        }
    }
}

// ---------- readout: out[p] = ssp(ps@W1+b1)@W2 + b2 (W2 is HDx1) ----------
__global__ __launch_bounds__(256) void readout_k(
        const float* __restrict__ ps,
        const float* __restrict__ W1, const float* __restrict__ b1,
        const float* __restrict__ W2, const float* __restrict__ b2,
        float* __restrict__ outp) {
    __shared__ float At[HD][68];
    __shared__ float parts[64][5];
    int m0 = blockIdx.x * 64;
    int t = threadIdx.x;
    stage_rows(ps, NPROBE, m0, t, At);
    __syncthreads();
    int jg = t & 63, eg = t >> 6;
    float acc0[16], acc1[16];
#pragma unroll
    for (int i = 0; i < 16; ++i) { acc0[i] = 0.f; acc1[i] = 0.f; }
    gemm_tile(W1, At, jg, eg, acc0, acc1);
    float bb0 = b1[jg], bb1 = b1[jg + 64];
    __syncthreads();
#pragma unroll
    for (int r8 = 0; r8 < 16; ++r8) {
        At[jg][eg * 16 + r8]      = sspf(acc0[r8] + bb0);
        At[jg + 64][eg * 16 + r8] = sspf(acc1[r8] + bb1);
    }
    __syncthreads();
    {
        int r = t >> 2, q = t & 3;
        float p = 0.f;
#pragma unroll 8
        for (int i = 0; i < 32; ++i) {
            int k = q * 32 + i;
            p = fmaf(At[k][r], W2[k], p);
        }
        parts[r][q] = p;
    }
    __syncthreads();
    if (t < 64) {
        int row = m0 + t;
        if (row < NPROBE)
            outp[row] = parts[t][0] + parts[t][1] + parts[t][2] + parts[t][3] + b2[0];
    }
}

// ---------- launcher ----------
extern "C" void kernel_launch(void* const* d_in, const int* in_sizes, int n_in,
                              void* d_out, int out_size, void* d_ws, size_t ws_size,
                              hipStream_t stream) {
    const float* atom_rep = (const float*)d_in[0];
    const float* dist     = (const float*)d_in[1];
    const float* We1 = (const float*)d_in[2];
    const float* be1 = (const float*)d_in[3];
    const float* We2 = (const float*)d_in[4];
    const float* be2 = (const float*)d_in[5];
    const float* Wn1 = (const float*)d_in[6];
    const float* bn1 = (const float*)d_in[7];
    const float* Wn2 = (const float*)d_in[8];
    const float* bn2 = (const float*)d_in[9];
    const float* gW1 = (const float*)d_in[10];
    const float* gb1 = (const float*)d_in[11];
    const float* gW2 = (const float*)d_in[12];
    const float* gb2 = (const float*)d_in[13];
    const float* tW1 = (const float*)d_in[14];
    const float* tb1 = (const float*)d_in[15];
    const float* tW2 = (const float*)d_in[16];
    const float* tb2 = (const float*)d_in[17];
    const float* rW1 = (const float*)d_in[18];
    const float* rb1 = (const float*)d_in[19];
    const float* rW2 = (const float*)d_in[20];
    const float* rb2 = (const float*)d_in[21];
    const int*   pe  = (const int*)d_in[22];
    float* out = (float*)d_out;

    float* ws = (float*)d_ws;
    float* ps     = ws;                                    // NPROBE*HD
    float* msgsum = ps + (size_t)NPROBE * HD;              // NPROBE*HD
    float* Xp     = msgsum + (size_t)NPROBE * HD;          // NPROBE*HD
    float* Gp     = Xp + (size_t)NPROBE * HD;              // NPROBE*HD
    float* Xa     = Gp + (size_t)NPROBE * HD;              // NLAYER*NATOM*HD
    float* gtab   = Xa + (size_t)NLAYER * NATOM * HD;      // NLAYER*(NBIN+1)*HD

    const int PBLK = (NPROBE + 63) / 64;   // 1563
    const int ABLK = (NATOM + 63) / 64;    // 313
    const int EBLK = NEDGE / 64;           // 6250

    hipMemsetAsync(ps, 0, (size_t)NPROBE * HD * sizeof(float), stream);
    gate_table_k<<<NLAYER * (NBIN + 1), HD, 0, stream>>>(We1, be1, We2, be2, gtab);
    for (int l = 0; l < NLAYER; ++l)
        gemm1_k<<<ABLK, 256, 0, stream>>>(atom_rep + (size_t)l * NATOM * HD, NATOM,
                                          Wn1 + (size_t)l * 2 * HD * HD,
                                          Xa + (size_t)l * NATOM * HD);
    for (int l = 0; l < NLAYER; ++l) {
        hipMemsetAsync(msgsum, 0, (size_t)NPROBE * HD * sizeof(float), stream);
        // Xp = probe_state @ Wn1[128:,:]
        gemm1_k<<<PBLK, 256, 0, stream>>>(ps, NPROBE,
                                          Wn1 + (size_t)l * 2 * HD * HD + (size_t)HD * HD,
                                          Xp);
        edge_msg_k<<<EBLK, 256, 0, stream>>>(Xa + (size_t)l * NATOM * HD, Xp,
                                             bn1 + l * HD,
                                             Wn2 + (size_t)l * HD * HD,
                                             bn2 + l * HD,
                                             gtab + (size_t)l * (NBIN + 1) * HD,
                                             dist, pe, msgsum);
        // gate vector g = sigmoid(mlp(ps))
        mlp2_k<<<PBLK, 256, 0, stream>>>(ps,
                                         gW1 + (size_t)l * HD * HD, gb1 + l * HD,
                                         gW2 + (size_t)l * HD * HD, gb2 + l * HD,
                                         Gp, nullptr, nullptr, 0);
        // ps = ps*g + (1-g)*mlp(msgsum)
        mlp2_k<<<PBLK, 256, 0, stream>>>(msgsum,
                                         tW1 + (size_t)l * HD * HD, tb1 + l * HD,
                                         tW2 + (size_t)l * HD * HD, tb2 + l * HD,
                                         ps, Gp, ps, 1);
    }
    readout_k<<<PBLK, 256, 0, stream>>>(ps, rW1, rb1, rW2, rb2, out);
}

// Round 2
// 1603.023 us; speedup vs baseline: 1.1260x; 1.1260x over previous
//
#include <hip/hip_runtime.h>

#define NLAYER 3
#define NATOM 20000
#define NPROBE 100000
#define NEDGE 400000
#define HD 128
#define NBIN 2048
#define CUTOFFF 4.0f
#define PLANE 16384   // ushorts per bf16 plane (128x128)

typedef unsigned int u32;
typedef unsigned short u16;
typedef __attribute__((ext_vector_type(8))) short bf16x8;
typedef __attribute__((ext_vector_type(4))) float f32x4;

// ---------- math helpers ----------
__device__ __forceinline__ float sspf(float x) {
    return fmaxf(x, 0.f) + __logf(1.f + __expf(-fabsf(x))) - 0.69314718055994530942f;
}
__device__ __forceinline__ float sigf(float x) {
    return 1.f / (1.f + __expf(-x));
}
__device__ __forceinline__ void atomic_add_f(float* p, float v) {
    __hip_atomic_fetch_add(p, v, __ATOMIC_RELAXED, __HIP_MEMORY_SCOPE_AGENT);
}
__device__ __forceinline__ u32 f2u(float f) { union { float f; u32 u; } x; x.f = f; return x.u; }
__device__ __forceinline__ float u2f(u32 u) { union { float f; u32 u; } x; x.u = u; return x.f; }
__device__ __forceinline__ u16 bf16rn(float f) {
    u32 u = f2u(f);
    u32 r = u + 0x7fffu + ((u >> 16) & 1u);
    return (u16)(r >> 16);
}
// pack float -> (hi bf16 | lo bf16 << 16), hi+lo ~ exact split
__device__ __forceinline__ u32 packhl(float x) {
    u16 h = bf16rn(x);
    float fh = u2f((u32)h << 16);
    u16 l = bf16rn(x - fh);
    return (u32)h | ((u32)l << 16);
}
__device__ __forceinline__ u32 lo16pair(u32 a, u32 b) { return (a & 0xffffu) | (b << 16); }
__device__ __forceinline__ u32 hi16pair(u32 a, u32 b) { return (a >> 16) | (b & 0xffff0000u); }
__device__ __forceinline__ bf16x8 mk_bf16x8(u32 a, u32 b, u32 c, u32 d) {
    union { u32 u[4]; bf16x8 v; } x;
    x.u[0] = a; x.u[1] = b; x.u[2] = c; x.u[3] = d;
    return x.v;
}

// ---------- MFMA GEMM core ----------
// LDS tile: 64 rows x 128 packed u32 (hi|lo bf16 per element), XOR-swizzled at
// 16B granules: granule g of row r stored at g ^ (r&7).
// Wave w computes rows w*16..w*16+15 x all 128 cols. acc[n][reg]:
// D row = wrow0 + (lane>>4)*4 + reg, col = n*16 + (lane&15).
// B frags: [chunk 0..3][n 0..7][lane 0..63] x 8 bf16, hi plane then lo plane.
__device__ __forceinline__ void mma_K128(const u32* __restrict__ lds,
                                         int lane, int wrow0,
                                         const bf16x8* __restrict__ Bh,
                                         const bf16x8* __restrict__ Bl,
                                         f32x4 acc[8]) {
    int row = wrow0 + (lane & 15);
    const u32* rp = lds + row * 128;
    int s = row & 7;
    int kq = (lane >> 4) << 1;
#pragma unroll
    for (int c = 0; c < 4; ++c) {
        int g0 = c * 8 + kq;
        const u32* p0 = rp + ((g0 ^ s) << 2);
        const u32* p1 = rp + (((g0 + 1) ^ s) << 2);
        u32 a0 = p0[0], a1 = p0[1], a2 = p0[2], a3 = p0[3];
        u32 b0 = p1[0], b1 = p1[1], b2 = p1[2], b3 = p1[3];
        bf16x8 Ah = mk_bf16x8(lo16pair(a0, a1), lo16pair(a2, a3),
                              lo16pair(b0, b1), lo16pair(b2, b3));
        bf16x8 Al = mk_bf16x8(hi16pair(a0, a1), hi16pair(a2, a3),
                              hi16pair(b0, b1), hi16pair(b2, b3));
        const bf16x8* bh = Bh + (size_t)(c * 8) * 64 + lane;
        const bf16x8* bl = Bl + (size_t)(c * 8) * 64 + lane;
#pragma unroll
        for (int n = 0; n < 8; ++n) {
            bf16x8 vh = bh[n * 64];
            bf16x8 vl = bl[n * 64];
            acc[n] = __builtin_amdgcn_mfma_f32_16x16x32_bf16(Ah, vh, acc[n], 0, 0, 0);
            acc[n] = __builtin_amdgcn_mfma_f32_16x16x32_bf16(Al, vh, acc[n], 0, 0, 0);
            acc[n] = __builtin_amdgcn_mfma_f32_16x16x32_bf16(Ah, vl, acc[n], 0, 0, 0);
        }
    }
}

// stage 64 fp32 rows -> packed u32 LDS (swizzled). thread t: row t>>2, quarter t&3.
__device__ __forceinline__ void stage_pack(const float* __restrict__ A, int M,
                                           int m0, int t, u32* lds) {
    int r = t >> 2, q = t & 3;
    int row = m0 + r;
    bool ok = row < M;
    const float4* src = (const float4*)(A + (size_t)row * HD + q * 32);
    int s = r & 7;
#pragma unroll
    for (int i4 = 0; i4 < 8; ++i4) {
        float4 v = ok ? src[i4] : make_float4(0.f, 0.f, 0.f, 0.f);
        u32 p0 = packhl(v.x), p1 = packhl(v.y), p2 = packhl(v.z), p3 = packhl(v.w);
        int g = q * 8 + i4;
        *(uint4*)(lds + r * 128 + ((g ^ s) << 2)) = make_uint4(p0, p1, p2, p3);
    }
}

// ---------- weight conversion: fp32 W[128][128] -> swizzled frag hi/lo planes ----------
__global__ void convert_w_k(const float* __restrict__ Wn1, const float* __restrict__ Wn2,
                            const float* __restrict__ gW1, const float* __restrict__ gW2,
                            const float* __restrict__ tW1, const float* __restrict__ tW2,
                            const float* __restrict__ rW1, u16* __restrict__ Wb) {
    int m = blockIdx.x;
    const float* src;
    if (m < 6)       src = Wn1 + (size_t)(m >> 1) * (2 * HD * HD) + (size_t)(m & 1) * (HD * HD);
    else if (m < 9)  src = Wn2 + (size_t)(m - 6) * HD * HD;
    else if (m < 12) src = gW1 + (size_t)(m - 9) * HD * HD;
    else if (m < 15) src = gW2 + (size_t)(m - 12) * HD * HD;
    else if (m < 18) src = tW1 + (size_t)(m - 15) * HD * HD;
    else if (m < 21) src = tW2 + (size_t)(m - 18) * HD * HD;
    else             src = rW1;
    int t = threadIdx.x;
    int lane = t & 63, nn = t >> 6;
    u16* dh = Wb + (size_t)m * (2 * PLANE);
    u16* dl = dh + PLANE;
    for (int c = 0; c < 4; ++c) {
        for (int hh = 0; hh < 2; ++hh) {
            int n = nn + hh * 4;
            int col = n * 16 + (lane & 15);
            int k0 = c * 32 + (lane >> 4) * 8;
            u32 hv[4], lv[4];
#pragma unroll
            for (int jj = 0; jj < 4; ++jj) {
                float wA = src[(size_t)(k0 + 2 * jj) * HD + col];
                float wB = src[(size_t)(k0 + 2 * jj + 1) * HD + col];
                u16 ha = bf16rn(wA), hb = bf16rn(wB);
                u16 la = bf16rn(wA - u2f((u32)ha << 16));
                u16 lb = bf16rn(wB - u2f((u32)hb << 16));
                hv[jj] = (u32)ha | ((u32)hb << 16);
                lv[jj] = (u32)la | ((u32)lb << 16);
            }
            size_t off = ((size_t)(c * 8 + n) * 64 + lane) * 8;
            *(uint4*)(dh + off) = make_uint4(hv[0], hv[1], hv[2], hv[3]);
            *(uint4*)(dl + off) = make_uint4(lv[0], lv[1], lv[2], lv[3]);
        }
    }
}

// ---------- gates lookup table (unchanged from round 0) ----------
__global__ void gate_table_k(const float* __restrict__ We1, const float* __restrict__ be1,
                             const float* __restrict__ We2, const float* __restrict__ be2,
                             float* __restrict__ gtab) {
    int row = blockIdx.x;
    int l = row / (NBIN + 1);
    int i = row % (NBIN + 1);
    int j = threadIdx.x;
    float d = (CUTOFFF / NBIN) * (float)i;
    __shared__ float h1[HD];
    const float* w1 = We1 + (size_t)l * 16 * HD;
    float acc = be1[l * HD + j];
#pragma unroll
    for (int k = 0; k < 16; ++k) {
        float dd = d - 0.25f * (float)k;
        float es = __expf(-dd * dd * 8.0f);
        acc = fmaf(es, w1[k * HD + j], acc);
    }
    h1[j] = sspf(acc);
    __syncthreads();
    const float* w2 = We2 + (size_t)l * HD * HD;
    float acc2 = be2[l * HD + j];
    for (int k = 0; k < HD; ++k) acc2 = fmaf(h1[k], w2[k * HD + j], acc2);
    float sc = 1.f - sigf(5.f * (d - (CUTOFFF - 1.5f)));
    gtab[(size_t)row * HD + j] = acc2 * sc;
}

// ---------- single GEMM: out = A @ W (fp32 out) ----------
__global__ __launch_bounds__(256, 4) void gemm1_mfma_k(const float* __restrict__ A, int M,
                                                       const u16* __restrict__ Wb1,
                                                       float* __restrict__ outp) {
    __shared__ u32 lds[64 * 128];
    int m0 = blockIdx.x * 64, t = threadIdx.x;
    stage_pack(A, M, m0, t, lds);
    __syncthreads();
    int lane = t & 63, wrow0 = (t >> 6) * 16;
    f32x4 acc[8] = {};
    mma_K128(lds, lane, wrow0, (const bf16x8*)Wb1, (const bf16x8*)(Wb1 + PLANE), acc);
    int l15 = lane & 15, lq = lane >> 4;
#pragma unroll
    for (int r = 0; r < 4; ++r) {
        int row = m0 + wrow0 + lq * 4 + r;
        if (row < M) {
            float* op = outp + (size_t)row * HD + l15;
#pragma unroll
            for (int n = 0; n < 8; ++n) op[n * 16] = acc[n][r];
        }
    }
}

// ---------- edge kernel ----------
__global__ __launch_bounds__(256, 4) void edge_msg_mfma_k(
        const float* __restrict__ Xa, const float* __restrict__ Xp,
        const float* __restrict__ bn1, const u16* __restrict__ W2b,
        const float* __restrict__ bn2, const float* __restrict__ gtab,
        const float* __restrict__ dist, const int* __restrict__ pe,
        float* __restrict__ msgsum) {
    __shared__ u32 lds[64 * 128];
    int e0 = blockIdx.x * 64;
    int t = threadIdx.x;
    {
        int r = t >> 2, q = t & 3;
        int e = e0 + r;
        int snd = pe[2 * e], rcv = pe[2 * e + 1];
        const float4* xa = (const float4*)(Xa + (size_t)snd * HD + q * 32);
        const float4* xp = (const float4*)(Xp + (size_t)rcv * HD + q * 32);
        const float4* bb = (const float4*)(bn1 + q * 32);
        int s = r & 7;
#pragma unroll
        for (int i4 = 0; i4 < 8; ++i4) {
            float4 va = xa[i4], vp = xp[i4], vb = bb[i4];
            u32 p0 = packhl(sspf(va.x + vp.x + vb.x));
            u32 p1 = packhl(sspf(va.y + vp.y + vb.y));
            u32 p2 = packhl(sspf(va.z + vp.z + vb.z));
            u32 p3 = packhl(sspf(va.w + vp.w + vb.w));
            int g = q * 8 + i4;
            *(uint4*)(lds + r * 128 + ((g ^ s) << 2)) = make_uint4(p0, p1, p2, p3);
        }
    }
    __syncthreads();
    int lane = t & 63, wrow0 = (t >> 6) * 16;
    f32x4 acc[8] = {};
    mma_K128(lds, lane, wrow0, (const bf16x8*)W2b, (const bf16x8*)(W2b + PLANE), acc);
    int l15 = lane & 15, lq = lane >> 4;
#pragma unroll
    for (int r = 0; r < 4; ++r) {
        int er = wrow0 + lq * 4 + r;
        int e = e0 + er;
        int rcv = pe[2 * e + 1];
        float d = dist[e];
        float x = d * ((float)NBIN / CUTOFFF);
        int i = (int)x;
        i = i < (NBIN - 1) ? i : (NBIN - 1);
        float f = x - (float)i;
        const float* gp = gtab + (size_t)i * HD;
        float* dst = msgsum + (size_t)rcv * HD;
#pragma unroll
        for (int n = 0; n < 8; ++n) {
            int col = n * 16 + l15;
            float ga = gp[col], gb = gp[HD + col];
            float gv = fmaf(gb - ga, f, ga);
            atomic_add_f(dst + col, (acc[n][r] + bn2[col]) * gv);
        }
    }
}

// ---------- fused 2-layer probe MLP (+ optional Xp = out @ W3 stage) ----------
// mode 0: outp = sigmoid(MLP(A))         (gate vector; Gp unused)
// mode 1: outp = outp*Gp + (1-Gp)*MLP(A); if W3b: xpout = outp @ W3
__global__ __launch_bounds__(256, 4) void mlp2_mfma_k(
        const float* __restrict__ A,
        const u16* __restrict__ W1b, const float* __restrict__ b1,
        const u16* __restrict__ W2b, const float* __restrict__ b2,
        const u16* __restrict__ W3b,
        const float* __restrict__ Gp,
        float* __restrict__ outp, float* __restrict__ xpout, int mode) {
    __shared__ u32 lds[64 * 128];
    int m0 = blockIdx.x * 64, t = threadIdx.x;
    stage_pack(A, NPROBE, m0, t, lds);
    __syncthreads();
    int lane = t & 63, wrow0 = (t >> 6) * 16;
    int l15 = lane & 15, lq = lane >> 4;
    f32x4 acc[8] = {};
    mma_K128(lds, lane, wrow0, (const bf16x8*)W1b, (const bf16x8*)(W1b + PLANE), acc);
    __syncthreads();
    // h = ssp(acc + b1) -> lds (packed, swizzled)
#pragma unroll
    for (int n = 0; n < 8; ++n) {
        float bb = b1[n * 16 + l15];
#pragma unroll
        for (int r = 0; r < 4; ++r) {
            int row = wrow0 + lq * 4 + r;
            int col = n * 16 + l15;
            float h = sspf(acc[n][r] + bb);
            lds[row * 128 + (((col >> 2) ^ (row & 7)) << 2) + (col & 3)] = packhl(h);
        }
    }
    __syncthreads();
    f32x4 acc2[8] = {};
    mma_K128(lds, lane, wrow0, (const bf16x8*)W2b, (const bf16x8*)(W2b + PLANE), acc2);
    if (mode == 0) {
#pragma unroll
        for (int r = 0; r < 4; ++r) {
            int row = m0 + wrow0 + lq * 4 + r;
            if (row < NPROBE) {
#pragma unroll
                for (int n = 0; n < 8; ++n) {
                    int col = n * 16 + l15;
                    outp[(size_t)row * HD + col] = sigf(acc2[n][r] + b2[col]);
                }
            }
        }
    } else {
        __syncthreads();
#pragma unroll
        for (int n = 0; n < 8; ++n) {
            float bb = b2[n * 16 + l15];
#pragma unroll
            for (int r = 0; r < 4; ++r) {
                int row = m0 + wrow0 + lq * 4 + r;
                int col = n * 16 + l15;
                if (row < NPROBE) {
                    size_t idx = (size_t)row * HD + col;
                    float tv = acc2[n][r] + bb;
                    float g = Gp[idx];
                    float val = fmaf(outp[idx] - tv, g, tv);  // ps*g + (1-g)*t
                    outp[idx] = val;
                    if (W3b) {
                        int lrow = wrow0 + lq * 4 + r;
                        lds[lrow * 128 + (((col >> 2) ^ (lrow & 7)) << 2) + (col & 3)] = packhl(val);
                    }
                }
            }
        }
        if (W3b) {
            __syncthreads();
            f32x4 acc3[8] = {};
            mma_K128(lds, lane, wrow0, (const bf16x8*)W3b, (const bf16x8*)(W3b + PLANE), acc3);
#pragma unroll
            for (int r = 0; r < 4; ++r) {
                int row = m0 + wrow0 + lq * 4 + r;
                if (row < NPROBE) {
#pragma unroll
                    for (int n = 0; n < 8; ++n)
                        xpout[(size_t)row * HD + n * 16 + l15] = acc3[n][r];
                }
            }
        }
    }
}

// ---------- readout (fp32, from round 0) ----------
__device__ __forceinline__ void stage_rows(const float* __restrict__ A, int M,
                                           int m0, int t, float (*At)[68]) {
    int r = t >> 2, q = t & 3;
    int row = m0 + r;
    const float* src = A + (size_t)row * HD + q * 32;
#pragma unroll
    for (int i4 = 0; i4 < 8; ++i4) {
        float4 v = make_float4(0.f, 0.f, 0.f, 0.f);
        if (row < M) v = *(const float4*)(src + i4 * 4);
        int k = q * 32 + i4 * 4;
        At[k + 0][r] = v.x; At[k + 1][r] = v.y;
        At[k + 2][r] = v.z; At[k + 3][r] = v.w;
    }
}
__device__ __forceinline__ void gemm_tile(const float* __restrict__ W,
                                          const float (*At)[68],
                                          int jg, int eg,
                                          float* acc0, float* acc1) {
#pragma unroll 4
    for (int k = 0; k < HD; ++k) {
        float w0 = W[k * HD + jg];
        float w1 = W[k * HD + jg + 64];
        const float* a = &At[k][eg * 16];
#pragma unroll
        for (int r4 = 0; r4 < 4; ++r4) {
            float4 av = *(const float4*)(a + r4 * 4);
            acc0[r4 * 4 + 0] = fmaf(av.x, w0, acc0[r4 * 4 + 0]);
            acc1[r4 * 4 + 0] = fmaf(av.x, w1, acc1[r4 * 4 + 0]);
            acc0[r4 * 4 + 1] = fmaf(av.y, w0, acc0[r4 * 4 + 1]);
            acc1[r4 * 4 + 1] = fmaf(av.y, w1, acc1[r4 * 4 + 1]);
            acc0[r4 * 4 + 2] = fmaf(av.z, w0, acc0[r4 * 4 + 2]);
            acc1[r4 * 4 + 2] = fmaf(av.z, w1, acc1[r4 * 4 + 2]);
            acc0[r4 * 4 + 3] = fmaf(av.w, w0, acc0[r4 * 4 + 3]);
            acc1[r4 * 4 + 3] = fmaf(av.w, w1, acc1[r4 * 4 + 3]);
        }
    }
}
__global__ __launch_bounds__(256) void readout_k(
        const float* __restrict__ ps,
        const float* __restrict__ W1, const float* __restrict__ b1,
        const float* __restrict__ W2, const float* __restrict__ b2,
        float* __restrict__ outp) {
    __shared__ float At[HD][68];
    __shared__ float parts[64][5];
    int m0 = blockIdx.x * 64;
    int t = threadIdx.x;
    stage_rows(ps, NPROBE, m0, t, At);
    __syncthreads();
    int jg = t & 63, eg = t >> 6;
    float acc0[16], acc1[16];
#pragma unroll
    for (int i = 0; i < 16; ++i) { acc0[i] = 0.f; acc1[i] = 0.f; }
    gemm_tile(W1, At, jg, eg, acc0, acc1);
    float bb0 = b1[jg], bb1 = b1[jg + 64];
    __syncthreads();
#pragma unroll
    for (int r8 = 0; r8 < 16; ++r8) {
        At[jg][eg * 16 + r8]      = sspf(acc0[r8] + bb0);
        At[jg + 64][eg * 16 + r8] = sspf(acc1[r8] + bb1);
    }
    __syncthreads();
    {
        int r = t >> 2, q = t & 3;
        float p = 0.f;
#pragma unroll 8
        for (int i = 0; i < 32; ++i) {
            int k = q * 32 + i;
            p = fmaf(At[k][r], W2[k], p);
        }
        parts[r][q] = p;
    }
    __syncthreads();
    if (t < 64) {
        int row = m0 + t;
        if (row < NPROBE)
            outp[row] = parts[t][0] + parts[t][1] + parts[t][2] + parts[t][3] + b2[0];
    }
}

// ---------- launcher ----------
extern "C" void kernel_launch(void* const* d_in, const int* in_sizes, int n_in,
                              void* d_out, int out_size, void* d_ws, size_t ws_size,
                              hipStream_t stream) {
    const float* atom_rep = (const float*)d_in[0];
    const float* dist     = (const float*)d_in[1];
    const float* We1 = (const float*)d_in[2];
    const float* be1 = (const float*)d_in[3];
    const float* We2 = (const float*)d_in[4];
    const float* be2 = (const float*)d_in[5];
    const float* Wn1 = (const float*)d_in[6];
    const float* bn1 = (const float*)d_in[7];
    const float* Wn2 = (const float*)d_in[8];
    const float* bn2 = (const float*)d_in[9];
    const float* gW1 = (const float*)d_in[10];
    const float* gb1 = (const float*)d_in[11];
    const float* gW2 = (const float*)d_in[12];
    const float* gb2 = (const float*)d_in[13];
    const float* tW1 = (const float*)d_in[14];
    const float* tb1 = (const float*)d_in[15];
    const float* tW2 = (const float*)d_in[16];
    const float* tb2 = (const float*)d_in[17];
    const float* rW1 = (const float*)d_in[18];
    const float* rb1 = (const float*)d_in[19];
    const float* rW2 = (const float*)d_in[20];
    const float* rb2 = (const float*)d_in[21];
    const int*   pe  = (const int*)d_in[22];
    float* out = (float*)d_out;

    float* ws = (float*)d_ws;
    float* ps     = ws;                         // 12,800,000 f
    float* msgsum = ps + 12800000u;             // 12,800,000 f
    float* Xp     = msgsum + 12800000u;         // 12,800,000 f
    float* Gp     = Xp + 12800000u;             // 12,800,000 f
    float* Xa     = Gp + 12800000u;             // 2,560,000 f (per-layer reuse)
    float* gtab   = Xa + 2560000u;              // 3*2049*128 = 786,816 f
    u16*   Wb     = (u16*)(gtab + 786816u);     // 22 matrices * 2 planes * 16384 u16

    const int PBLK = (NPROBE + 63) / 64;   // 1563
    const int ABLK = (NATOM + 63) / 64;    // 313
    const int EBLK = NEDGE / 64;           // 6250

    hipMemsetAsync(ps, 0, 12800000ull * 4, stream);
    hipMemsetAsync(Xp, 0, 12800000ull * 4, stream);
    convert_w_k<<<22, 256, 0, stream>>>(Wn1, Wn2, gW1, gW2, tW1, tW2, rW1, Wb);
    gate_table_k<<<NLAYER * (NBIN + 1), HD, 0, stream>>>(We1, be1, We2, be2, gtab);

    for (int l = 0; l < NLAYER; ++l) {
        gemm1_mfma_k<<<ABLK, 256, 0, stream>>>(atom_rep + (size_t)l * NATOM * HD, NATOM,
                                               Wb + (size_t)(2 * l) * 2 * PLANE, Xa);
        hipMemsetAsync(msgsum, 0, 12800000ull * 4, stream);
        edge_msg_mfma_k<<<EBLK, 256, 0, stream>>>(Xa, Xp, bn1 + l * HD,
                                                  Wb + (size_t)(6 + l) * 2 * PLANE,
                                                  bn2 + l * HD,
                                                  gtab + (size_t)l * (NBIN + 1) * HD,
                                                  dist, pe, msgsum);
        mlp2_mfma_k<<<PBLK, 256, 0, stream>>>(ps,
                                              Wb + (size_t)(9 + l) * 2 * PLANE, gb1 + l * HD,
                                              Wb + (size_t)(12 + l) * 2 * PLANE, gb2 + l * HD,
                                              nullptr, nullptr, Gp, nullptr, 0);
        const u16* W3 = (l < NLAYER - 1) ? Wb + (size_t)(2 * (l + 1) + 1) * 2 * PLANE : nullptr;
        mlp2_mfma_k<<<PBLK, 256, 0, stream>>>(msgsum,
                                              Wb + (size_t)(15 + l) * 2 * PLANE, tb1 + l * HD,
                                              Wb + (size_t)(18 + l) * 2 * PLANE, tb2 + l * HD,
                                              W3, Gp, ps, Xp, 1);
    }
    readout_k<<<PBLK, 256, 0, stream>>>(ps, rW1, rb1, rW2, rb2, out);
}

// Round 3
// 1412.889 us; speedup vs baseline: 1.2775x; 1.1346x over previous
//
#include <hip/hip_runtime.h>

#define NLAYER 3
#define NATOM 20000
#define NPROBE 100000
#define NEDGE 400000
#define HD 128
#define NBIN 2048
#define CUTOFFF 4.0f
#define PLANE 16384   // ushorts per bf16 plane (128x128)

typedef unsigned int u32;
typedef unsigned short u16;
typedef __attribute__((ext_vector_type(8))) short bf16x8;
typedef __attribute__((ext_vector_type(4))) float f32x4;

// ---------- math helpers ----------
__device__ __forceinline__ float sspf(float x) {
    return fmaxf(x, 0.f) + __logf(1.f + __expf(-fabsf(x))) - 0.69314718055994530942f;
}
__device__ __forceinline__ float sigf(float x) {
    return 1.f / (1.f + __expf(-x));
}
__device__ __forceinline__ void atomic_add_f(float* p, float v) {
    __hip_atomic_fetch_add(p, v, __ATOMIC_RELAXED, __HIP_MEMORY_SCOPE_AGENT);
}
__device__ __forceinline__ u32 atomic_add_u(u32* p, u32 v) {
    return __hip_atomic_fetch_add(p, v, __ATOMIC_RELAXED, __HIP_MEMORY_SCOPE_AGENT);
}
__device__ __forceinline__ u32 f2u(float f) { union { float f; u32 u; } x; x.f = f; return x.u; }
__device__ __forceinline__ float u2f(u32 u) { union { float f; u32 u; } x; x.u = u; return x.f; }
__device__ __forceinline__ u16 bf16rn(float f) {
    u32 u = f2u(f);
    u32 r = u + 0x7fffu + ((u >> 16) & 1u);
    return (u16)(r >> 16);
}
// pack float -> (hi bf16 | lo bf16 << 16)
__device__ __forceinline__ u32 packhl(float x) {
    u16 h = bf16rn(x);
    float fh = u2f((u32)h << 16);
    u16 l = bf16rn(x - fh);
    return (u32)h | ((u32)l << 16);
}
__device__ __forceinline__ u32 lo16pair(u32 a, u32 b) { return (a & 0xffffu) | (b << 16); }
__device__ __forceinline__ u32 hi16pair(u32 a, u32 b) { return (a >> 16) | (b & 0xffff0000u); }
__device__ __forceinline__ bf16x8 mk_bf16x8(u32 a, u32 b, u32 c, u32 d) {
    union { u32 u[4]; bf16x8 v; } x;
    x.u[0] = a; x.u[1] = b; x.u[2] = c; x.u[3] = d;
    return x.v;
}

// ---------- MFMA GEMM core (as validated in round 2) ----------
__device__ __forceinline__ void mma_K128(const u32* __restrict__ lds,
                                         int lane, int wrow0,
                                         const bf16x8* __restrict__ Bh,
                                         const bf16x8* __restrict__ Bl,
                                         f32x4 acc[8]) {
    int row = wrow0 + (lane & 15);
    const u32* rp = lds + row * 128;
    int s = row & 7;
    int kq = (lane >> 4) << 1;
#pragma unroll
    for (int c = 0; c < 4; ++c) {
        int g0 = c * 8 + kq;
        const u32* p0 = rp + ((g0 ^ s) << 2);
        const u32* p1 = rp + (((g0 + 1) ^ s) << 2);
        u32 a0 = p0[0], a1 = p0[1], a2 = p0[2], a3 = p0[3];
        u32 b0 = p1[0], b1 = p1[1], b2 = p1[2], b3 = p1[3];
        bf16x8 Ah = mk_bf16x8(lo16pair(a0, a1), lo16pair(a2, a3),
                              lo16pair(b0, b1), lo16pair(b2, b3));
        bf16x8 Al = mk_bf16x8(hi16pair(a0, a1), hi16pair(a2, a3),
                              hi16pair(b0, b1), hi16pair(b2, b3));
        const bf16x8* bh = Bh + (size_t)(c * 8) * 64 + lane;
        const bf16x8* bl = Bl + (size_t)(c * 8) * 64 + lane;
#pragma unroll
        for (int n = 0; n < 8; ++n) {
            bf16x8 vh = bh[n * 64];
            bf16x8 vl = bl[n * 64];
            acc[n] = __builtin_amdgcn_mfma_f32_16x16x32_bf16(Ah, vh, acc[n], 0, 0, 0);
            acc[n] = __builtin_amdgcn_mfma_f32_16x16x32_bf16(Al, vh, acc[n], 0, 0, 0);
            acc[n] = __builtin_amdgcn_mfma_f32_16x16x32_bf16(Ah, vl, acc[n], 0, 0, 0);
        }
    }
}

__device__ __forceinline__ void stage_pack(const float* __restrict__ A, int M,
                                           int m0, int t, u32* lds) {
    int r = t >> 2, q = t & 3;
    int row = m0 + r;
    bool ok = row < M;
    const float4* src = (const float4*)(A + (size_t)row * HD + q * 32);
    int s = r & 7;
#pragma unroll
    for (int i4 = 0; i4 < 8; ++i4) {
        float4 v = ok ? src[i4] : make_float4(0.f, 0.f, 0.f, 0.f);
        u32 p0 = packhl(v.x), p1 = packhl(v.y), p2 = packhl(v.z), p3 = packhl(v.w);
        int g = q * 8 + i4;
        *(uint4*)(lds + r * 128 + ((g ^ s) << 2)) = make_uint4(p0, p1, p2, p3);
    }
}

// write ssp(acc+bias) back to LDS (packed, swizzled)
__device__ __forceinline__ void h_to_lds(u32* lds, int wrow0, int lq, int l15,
                                         const f32x4 acc[8], const float* __restrict__ bias) {
#pragma unroll
    for (int n = 0; n < 8; ++n) {
        float bb = bias[n * 16 + l15];
#pragma unroll
        for (int r = 0; r < 4; ++r) {
            int row = wrow0 + lq * 4 + r;
            int col = n * 16 + l15;
            lds[row * 128 + (((col >> 2) ^ (row & 7)) << 2) + (col & 3)] = packhl(sspf(acc[n][r] + bb));
        }
    }
}

// ---------- weight conversion ----------
__global__ void convert_w_k(const float* __restrict__ Wn1, const float* __restrict__ Wn2,
                            const float* __restrict__ gW1, const float* __restrict__ gW2,
                            const float* __restrict__ tW1, const float* __restrict__ tW2,
                            const float* __restrict__ rW1, u16* __restrict__ Wb) {
    int m = blockIdx.x;
    const float* src;
    if (m < 6)       src = Wn1 + (size_t)(m >> 1) * (2 * HD * HD) + (size_t)(m & 1) * (HD * HD);
    else if (m < 9)  src = Wn2 + (size_t)(m - 6) * HD * HD;
    else if (m < 12) src = gW1 + (size_t)(m - 9) * HD * HD;
    else if (m < 15) src = gW2 + (size_t)(m - 12) * HD * HD;
    else if (m < 18) src = tW1 + (size_t)(m - 15) * HD * HD;
    else if (m < 21) src = tW2 + (size_t)(m - 18) * HD * HD;
    else             src = rW1;
    int t = threadIdx.x;
    int lane = t & 63, nn = t >> 6;
    u16* dh = Wb + (size_t)m * (2 * PLANE);
    u16* dl = dh + PLANE;
    for (int c = 0; c < 4; ++c) {
        for (int hh = 0; hh < 2; ++hh) {
            int n = nn + hh * 4;
            int col = n * 16 + (lane & 15);
            int k0 = c * 32 + (lane >> 4) * 8;
            u32 hv[4], lv[4];
#pragma unroll
            for (int jj = 0; jj < 4; ++jj) {
                float wA = src[(size_t)(k0 + 2 * jj) * HD + col];
                float wB = src[(size_t)(k0 + 2 * jj + 1) * HD + col];
                u16 ha = bf16rn(wA), hb = bf16rn(wB);
                u16 la = bf16rn(wA - u2f((u32)ha << 16));
                u16 lb = bf16rn(wB - u2f((u32)hb << 16));
                hv[jj] = (u32)ha | ((u32)hb << 16);
                lv[jj] = (u32)la | ((u32)lb << 16);
            }
            size_t off = ((size_t)(c * 8 + n) * 64 + lane) * 8;
            *(uint4*)(dh + off) = make_uint4(hv[0], hv[1], hv[2], hv[3]);
            *(uint4*)(dl + off) = make_uint4(lv[0], lv[1], lv[2], lv[3]);
        }
    }
}

// ---------- gates lookup table ----------
__global__ void gate_table_k(const float* __restrict__ We1, const float* __restrict__ be1,
                             const float* __restrict__ We2, const float* __restrict__ be2,
                             float* __restrict__ gtab) {
    int row = blockIdx.x;
    int l = row / (NBIN + 1);
    int i = row % (NBIN + 1);
    int j = threadIdx.x;
    float d = (CUTOFFF / NBIN) * (float)i;
    __shared__ float h1[HD];
    const float* w1 = We1 + (size_t)l * 16 * HD;
    float acc = be1[l * HD + j];
#pragma unroll
    for (int k = 0; k < 16; ++k) {
        float dd = d - 0.25f * (float)k;
        float es = __expf(-dd * dd * 8.0f);
        acc = fmaf(es, w1[k * HD + j], acc);
    }
    h1[j] = sspf(acc);
    __syncthreads();
    const float* w2 = We2 + (size_t)l * HD * HD;
    float acc2 = be2[l * HD + j];
    for (int k = 0; k < HD; ++k) acc2 = fmaf(h1[k], w2[k * HD + j], acc2);
    float sc = 1.f - sigf(5.f * (d - (CUTOFFF - 1.5f)));
    gtab[(size_t)row * HD + j] = acc2 * sc;
}

// ---------- CSR sort kernels ----------
__global__ __launch_bounds__(256) void hist_k(const int* __restrict__ pe, u32* __restrict__ cnt) {
    int e = blockIdx.x * 256 + threadIdx.x;
    if (e < NEDGE) atomic_add_u(&cnt[pe[2 * e + 1]], 1u);
}

__global__ __launch_bounds__(1024) void scan_k(const u32* __restrict__ cnt, u32* __restrict__ cur) {
    __shared__ u32 sums[1024];
    int t = threadIdx.x;
    const int CH = (NPROBE + 1023) / 1024;   // 98
    int lo = t * CH, hi = lo + CH;
    if (hi > NPROBE) hi = NPROBE;
    u32 s = 0;
    for (int i = lo; i < hi; ++i) s += cnt[i];
    sums[t] = s;
    __syncthreads();
    for (int d = 1; d < 1024; d <<= 1) {
        u32 v = (t >= d) ? sums[t - d] : 0u;
        __syncthreads();
        sums[t] += v;
        __syncthreads();
    }
    u32 base = (t == 0) ? 0u : sums[t - 1];
    for (int i = lo; i < hi; ++i) {
        cur[i] = base;
        base += cnt[i];
    }
}

__global__ __launch_bounds__(256) void scatter_k(const int* __restrict__ pe,
                                                 u32* __restrict__ cur, u32* __restrict__ eord) {
    int e = blockIdx.x * 256 + threadIdx.x;
    if (e < NEDGE) {
        u32 pos = atomic_add_u(&cur[pe[2 * e + 1]], 1u);
        eord[pos] = (u32)e;
    }
}

// ---------- atom projection: Xa = atom_rep[l] @ Wn1_atom ----------
__global__ __launch_bounds__(256, 4) void gemm1_mfma_k(const float* __restrict__ A, int M,
                                                       const u16* __restrict__ Wb1,
                                                       float* __restrict__ outp) {
    __shared__ u32 lds[64 * 128];
    int m0 = blockIdx.x * 64, t = threadIdx.x;
    stage_pack(A, M, m0, t, lds);
    __syncthreads();
    int lane = t & 63, wrow0 = (t >> 6) * 16;
    f32x4 acc[8] = {};
    mma_K128(lds, lane, wrow0, (const bf16x8*)Wb1, (const bf16x8*)(Wb1 + PLANE), acc);
    int l15 = lane & 15, lq = lane >> 4;
#pragma unroll
    for (int r = 0; r < 4; ++r) {
        int row = m0 + wrow0 + lq * 4 + r;
        if (row < M) {
            float* op = outp + (size_t)row * HD + l15;
#pragma unroll
            for (int n = 0; n < 8; ++n) op[n * 16] = acc[n][r];
        }
    }
}

// ---------- edge kernel (receiver-sorted, merged atomics) ----------
__global__ __launch_bounds__(256, 4) void edge_msg_mfma_k(
        const float* __restrict__ Xa, const float* __restrict__ Xp,
        const float* __restrict__ bn1, const u16* __restrict__ W2b,
        const float* __restrict__ bn2, const float* __restrict__ gtab,
        const float* __restrict__ dist, const int* __restrict__ pe,
        const u32* __restrict__ eord, float* __restrict__ msgsum) {
    __shared__ u32 lds[64 * 128];
    __shared__ int rcv_s[64];
    __shared__ float d_s[64];
    int e0 = blockIdx.x * 64;
    int t = threadIdx.x;
    {
        int r = t >> 2, q = t & 3;
        int e = (int)eord[e0 + r];
        int snd = pe[2 * e], rcv = pe[2 * e + 1];
        if (q == 0) { rcv_s[r] = rcv; d_s[r] = dist[e]; }
        const float4* xa = (const float4*)(Xa + (size_t)snd * HD + q * 32);
        const float4* xp = (const float4*)(Xp + (size_t)rcv * HD + q * 32);
        const float4* bb = (const float4*)(bn1 + q * 32);
        int s = r & 7;
#pragma unroll
        for (int i4 = 0; i4 < 8; ++i4) {
            float4 va = xa[i4], vp = xp[i4], vb = bb[i4];
            u32 p0 = packhl(sspf(va.x + vp.x + vb.x));
            u32 p1 = packhl(sspf(va.y + vp.y + vb.y));
            u32 p2 = packhl(sspf(va.z + vp.z + vb.z));
            u32 p3 = packhl(sspf(va.w + vp.w + vb.w));
            int g = q * 8 + i4;
            *(uint4*)(lds + r * 128 + ((g ^ s) << 2)) = make_uint4(p0, p1, p2, p3);
        }
    }
    __syncthreads();
    int lane = t & 63, wrow0 = (t >> 6) * 16;
    f32x4 acc[8] = {};
    mma_K128(lds, lane, wrow0, (const bf16x8*)W2b, (const bf16x8*)(W2b + PLANE), acc);
    int l15 = lane & 15, lq = lane >> 4;

    int rcvr[4];
    float fr[4];
    const float* gp[4];
#pragma unroll
    for (int r = 0; r < 4; ++r) {
        int er = wrow0 + lq * 4 + r;
        rcvr[r] = rcv_s[er];
        float x = d_s[er] * ((float)NBIN / CUTOFFF);
        int i = (int)x;
        i = i < (NBIN - 1) ? i : (NBIN - 1);
        fr[r] = x - (float)i;
        gp[r] = gtab + (size_t)i * HD;
    }
    // apply bias + gate
#pragma unroll
    for (int n = 0; n < 8; ++n) {
        int col = n * 16 + l15;
        float bb = bn2[col];
#pragma unroll
        for (int r = 0; r < 4; ++r) {
            float ga = gp[r][col], gb = gp[r][HD + col];
            acc[n][r] = (acc[n][r] + bb) * fmaf(gb - ga, fr[r], ga);
        }
    }
    // in-thread run merge (rows are consecutive sorted edges), then atomics
#pragma unroll
    for (int r = 3; r >= 1; --r) {
        if (rcvr[r] == rcvr[r - 1]) {
#pragma unroll
            for (int n = 0; n < 8; ++n) acc[n][r - 1] += acc[n][r];
        } else {
            float* dst = msgsum + (size_t)rcvr[r] * HD + l15;
#pragma unroll
            for (int n = 0; n < 8; ++n) atomic_add_f(dst + n * 16, acc[n][r]);
        }
    }
    {
        float* dst = msgsum + (size_t)rcvr[0] * HD + l15;
#pragma unroll
        for (int n = 0; n < 8; ++n) atomic_add_f(dst + n * 16, acc[n][0]);
    }
}

// ---------- fused probe update: g=sig(MLP_g(ps)); ps=ps*g+(1-g)*MLP_t(msgsum); Xp=ps@W3 ----------
__global__ __launch_bounds__(256, 4) void probe_update_k(
        const float* __restrict__ ps, const float* __restrict__ msgsum,
        const u16* __restrict__ gW1b, const float* __restrict__ gb1,
        const u16* __restrict__ gW2b, const float* __restrict__ gb2,
        const u16* __restrict__ tW1b, const float* __restrict__ tb1,
        const u16* __restrict__ tW2b, const float* __restrict__ tb2,
        const u16* __restrict__ W3b,
        float* __restrict__ psout, float* __restrict__ xpout) {
    __shared__ u32 lds[64 * 128];
    int m0 = blockIdx.x * 64, t = threadIdx.x;
    int lane = t & 63, wrow0 = (t >> 6) * 16;
    int l15 = lane & 15, lq = lane >> 4;

    // ---- gate path ----
    stage_pack(ps, NPROBE, m0, t, lds);
    __syncthreads();
    f32x4 g[8] = {};
    mma_K128(lds, lane, wrow0, (const bf16x8*)gW1b, (const bf16x8*)(gW1b + PLANE), g);
    __syncthreads();
    h_to_lds(lds, wrow0, lq, l15, g, gb1);
    __syncthreads();
#pragma unroll
    for (int n = 0; n < 8; ++n) g[n] = (f32x4){0.f, 0.f, 0.f, 0.f};
    mma_K128(lds, lane, wrow0, (const bf16x8*)gW2b, (const bf16x8*)(gW2b + PLANE), g);
#pragma unroll
    for (int n = 0; n < 8; ++n) {
        float bb = gb2[n * 16 + l15];
#pragma unroll
        for (int r = 0; r < 4; ++r) g[n][r] = sigf(g[n][r] + bb);
    }
    // ---- trans path ----
    __syncthreads();
    stage_pack(msgsum, NPROBE, m0, t, lds);
    __syncthreads();
    f32x4 tv[8] = {};
    mma_K128(lds, lane, wrow0, (const bf16x8*)tW1b, (const bf16x8*)(tW1b + PLANE), tv);
    __syncthreads();
    h_to_lds(lds, wrow0, lq, l15, tv, tb1);
    __syncthreads();
#pragma unroll
    for (int n = 0; n < 8; ++n) tv[n] = (f32x4){0.f, 0.f, 0.f, 0.f};
    mma_K128(lds, lane, wrow0, (const bf16x8*)tW2b, (const bf16x8*)(tW2b + PLANE), tv);

    // ---- combine + write, keep val for optional Xp projection ----
    if (W3b) __syncthreads();
#pragma unroll
    for (int n = 0; n < 8; ++n) {
        float bb = tb2[n * 16 + l15];
        int col = n * 16 + l15;
#pragma unroll
        for (int r = 0; r < 4; ++r) {
            int row = m0 + wrow0 + lq * 4 + r;
            if (row < NPROBE) {
                size_t idx = (size_t)row * HD + col;
                float tval = tv[n][r] + bb;
                float val = fmaf(ps[idx] - tval, g[n][r], tval);  // ps*g + (1-g)*t
                psout[idx] = val;
                tv[n][r] = val;
            } else {
                tv[n][r] = 0.f;
            }
            if (W3b) {
                int lrow = wrow0 + lq * 4 + r;
                lds[lrow * 128 + (((col >> 2) ^ (lrow & 7)) << 2) + (col & 3)] = packhl(tv[n][r]);
            }
        }
    }
    if (W3b) {
        __syncthreads();
        f32x4 acc3[8] = {};
        mma_K128(lds, lane, wrow0, (const bf16x8*)W3b, (const bf16x8*)(W3b + PLANE), acc3);
#pragma unroll
        for (int r = 0; r < 4; ++r) {
            int row = m0 + wrow0 + lq * 4 + r;
            if (row < NPROBE) {
#pragma unroll
                for (int n = 0; n < 8; ++n)
                    xpout[(size_t)row * HD + n * 16 + l15] = acc3[n][r];
            }
        }
    }
}

// ---------- readout ----------
__device__ __forceinline__ void stage_rows(const float* __restrict__ A, int M,
                                           int m0, int t, float (*At)[68]) {
    int r = t >> 2, q = t & 3;
    int row = m0 + r;
    const float* src = A + (size_t)row * HD + q * 32;
#pragma unroll
    for (int i4 = 0; i4 < 8; ++i4) {
        float4 v = make_float4(0.f, 0.f, 0.f, 0.f);
        if (row < M) v = *(const float4*)(src + i4 * 4);
        int k = q * 32 + i4 * 4;
        At[k + 0][r] = v.x; At[k + 1][r] = v.y;
        At[k + 2][r] = v.z; At[k + 3][r] = v.w;
    }
}
__device__ __forceinline__ void gemm_tile(const float* __restrict__ W,
                                          const float (*At)[68],
                                          int jg, int eg,
                                          float* acc0, float* acc1) {
#pragma unroll 4
    for (int k = 0; k < HD; ++k) {
        float w0 = W[k * HD + jg];
        float w1 = W[k * HD + jg + 64];
        const float* a = &At[k][eg * 16];
#pragma unroll
        for (int r4 = 0; r4 < 4; ++r4) {
            float4 av = *(const float4*)(a + r4 * 4);
            acc0[r4 * 4 + 0] = fmaf(av.x, w0, acc0[r4 * 4 + 0]);
            acc1[r4 * 4 + 0] = fmaf(av.x, w1, acc1[r4 * 4 + 0]);
            acc0[r4 * 4 + 1] = fmaf(av.y, w0, acc0[r4 * 4 + 1]);
            acc1[r4 * 4 + 1] = fmaf(av.y, w1, acc1[r4 * 4 + 1]);
            acc0[r4 * 4 + 2] = fmaf(av.z, w0, acc0[r4 * 4 + 2]);
            acc1[r4 * 4 + 2] = fmaf(av.z, w1, acc1[r4 * 4 + 2]);
            acc0[r4 * 4 + 3] = fmaf(av.w, w0, acc0[r4 * 4 + 3]);
            acc1[r4 * 4 + 3] = fmaf(av.w, w1, acc1[r4 * 4 + 3]);
        }
    }
}
__global__ __launch_bounds__(256) void readout_k(
        const float* __restrict__ ps,
        const float* __restrict__ W1, const float* __restrict__ b1,
        const float* __restrict__ W2, const float* __restrict__ b2,
        float* __restrict__ outp) {
    __shared__ float At[HD][68];
    __shared__ float parts[64][5];
    int m0 = blockIdx.x * 64;
    int t = threadIdx.x;
    stage_rows(ps, NPROBE, m0, t, At);
    __syncthreads();
    int jg = t & 63, eg = t >> 6;
    float acc0[16], acc1[16];
#pragma unroll
    for (int i = 0; i < 16; ++i) { acc0[i] = 0.f; acc1[i] = 0.f; }
    gemm_tile(W1, At, jg, eg, acc0, acc1);
    float bb0 = b1[jg], bb1 = b1[jg + 64];
    __syncthreads();
#pragma unroll
    for (int r8 = 0; r8 < 16; ++r8) {
        At[jg][eg * 16 + r8]      = sspf(acc0[r8] + bb0);
        At[jg + 64][eg * 16 + r8] = sspf(acc1[r8] + bb1);
    }
    __syncthreads();
    {
        int r = t >> 2, q = t & 3;
        float p = 0.f;
#pragma unroll 8
        for (int i = 0; i < 32; ++i) {
            int k = q * 32 + i;
            p = fmaf(At[k][r], W2[k], p);
        }
        parts[r][q] = p;
    }
    __syncthreads();
    if (t < 64) {
        int row = m0 + t;
        if (row < NPROBE)
            outp[row] = parts[t][0] + parts[t][1] + parts[t][2] + parts[t][3] + b2[0];
    }
}

// ---------- launcher ----------
extern "C" void kernel_launch(void* const* d_in, const int* in_sizes, int n_in,
                              void* d_out, int out_size, void* d_ws, size_t ws_size,
                              hipStream_t stream) {
    const float* atom_rep = (const float*)d_in[0];
    const float* dist     = (const float*)d_in[1];
    const float* We1 = (const float*)d_in[2];
    const float* be1 = (const float*)d_in[3];
    const float* We2 = (const float*)d_in[4];
    const float* be2 = (const float*)d_in[5];
    const float* Wn1 = (const float*)d_in[6];
    const float* bn1 = (const float*)d_in[7];
    const float* Wn2 = (const float*)d_in[8];
    const float* bn2 = (const float*)d_in[9];
    const float* gW1 = (const float*)d_in[10];
    const float* gb1 = (const float*)d_in[11];
    const float* gW2 = (const float*)d_in[12];
    const float* gb2 = (const float*)d_in[13];
    const float* tW1 = (const float*)d_in[14];
    const float* tb1 = (const float*)d_in[15];
    const float* tW2 = (const float*)d_in[16];
    const float* tb2 = (const float*)d_in[17];
    const float* rW1 = (const float*)d_in[18];
    const float* rb1 = (const float*)d_in[19];
    const float* rW2 = (const float*)d_in[20];
    const float* rb2 = (const float*)d_in[21];
    const int*   pe  = (const int*)d_in[22];
    float* out = (float*)d_out;

    float* ws = (float*)d_ws;
    float* ps     = ws;                         // 12,800,000 f
    float* msgsum = ps + 12800000u;             // 12,800,000 f
    float* Xp     = msgsum + 12800000u;         // 12,800,000 f
    float* Xa     = Xp + 12800000u;             // 2,560,000 f
    float* gtab   = Xa + 2560000u;              // 786,816 f
    u16*   Wb     = (u16*)(gtab + 786816u);     // 22*2*PLANE u16
    u32*   cnt    = (u32*)(Wb + 22 * 2 * PLANE);
    u32*   cur    = cnt + NPROBE;
    u32*   eord   = cur + NPROBE;

    const int PBLK = (NPROBE + 63) / 64;   // 1563
    const int ABLK = (NATOM + 63) / 64;    // 313
    const int EBLK = NEDGE / 64;           // 6250
    const int TBLK = (NEDGE + 255) / 256;  // 1563

    hipMemsetAsync(ps, 0, 12800000ull * 4, stream);
    hipMemsetAsync(Xp, 0, 12800000ull * 4, stream);
    hipMemsetAsync(cnt, 0, (size_t)NPROBE * 4, stream);
    convert_w_k<<<22, 256, 0, stream>>>(Wn1, Wn2, gW1, gW2, tW1, tW2, rW1, Wb);
    gate_table_k<<<NLAYER * (NBIN + 1), HD, 0, stream>>>(We1, be1, We2, be2, gtab);
    hist_k<<<TBLK, 256, 0, stream>>>(pe, cnt);
    scan_k<<<1, 1024, 0, stream>>>(cnt, cur);
    scatter_k<<<TBLK, 256, 0, stream>>>(pe, cur, eord);

    for (int l = 0; l < NLAYER; ++l) {
        gemm1_mfma_k<<<ABLK, 256, 0, stream>>>(atom_rep + (size_t)l * NATOM * HD, NATOM,
                                               Wb + (size_t)(2 * l) * 2 * PLANE, Xa);
        hipMemsetAsync(msgsum, 0, 12800000ull * 4, stream);
        edge_msg_mfma_k<<<EBLK, 256, 0, stream>>>(Xa, Xp, bn1 + l * HD,
                                                  Wb + (size_t)(6 + l) * 2 * PLANE,
                                                  bn2 + l * HD,
                                                  gtab + (size_t)l * (NBIN + 1) * HD,
                                                  dist, pe, eord, msgsum);
        const u16* W3 = (l < NLAYER - 1) ? Wb + (size_t)(2 * (l + 1) + 1) * 2 * PLANE : nullptr;
        probe_update_k<<<PBLK, 256, 0, stream>>>(ps, msgsum,
                                                 Wb + (size_t)(9 + l) * 2 * PLANE, gb1 + l * HD,
                                                 Wb + (size_t)(12 + l) * 2 * PLANE, gb2 + l * HD,
                                                 Wb + (size_t)(15 + l) * 2 * PLANE, tb1 + l * HD,
                                                 Wb + (size_t)(18 + l) * 2 * PLANE, tb2 + l * HD,
                                                 W3, ps, Xp);
    }
    readout_k<<<PBLK, 256, 0, stream>>>(ps, rW1, rb1, rW2, rb2, out);
}